// Round 1
// baseline (2710.321 us; speedup 1.0000x reference)
//
#include <hip/hip_runtime.h>
#include <hip/hip_bf16.h>
#include <stdint.h>

#define NB  128
#define NP  512
#define KNN 16
#define CH  64
#define BPP 4   // points per block in MLP phases

// ---------------- workspace layout (bytes) ----------------
#define OFF_IDX    0
#define IDX_BYTES  (NB * NP * KNN * 4)            // 4,194,304
#define OFF_PART   (OFF_IDX + IDX_BYTES)
#define PART_BYTES (4 * 64 * 2 * 64 * 4)          // 131,072: [layer][slot][sum/ssq][ch]
#define OFF_BN     (OFF_PART + PART_BYTES)
#define BN_BYTES   (4 * 2 * 64 * 4)               // 2,048: [layer][scale/shift][ch]
#define OFF_WC     (OFF_BN + BN_BYTES)            // 16,384: Wc = W0a - W0b
#define OFF_WN     (OFF_WC + 4096 * 4)            // 16,384: Wn = W0b

// ---------------- weight prep: fold the center trick ----------------
__global__ void prep_weights(const float* __restrict__ W0,
                             float* __restrict__ Wc, float* __restrict__ Wn) {
    int i = blockIdx.x * 256 + threadIdx.x;       // i = o*64 + c, 4096 total
    if (i < 4096) {
        int oo = i >> 6, c = i & 63;
        float a = W0[oo * 128 + c];
        float b = W0[oo * 128 + 64 + c];
        Wc[i] = a - b;
        Wn[i] = b;
    }
}

// ---------------- KNN: replicate reference arithmetic exactly ----------------
__global__ __launch_bounds__(256)
void knn_kernel(const float* __restrict__ pts, int* __restrict__ idx) {
#pragma clang fp contract(off)
    __shared__ __align__(16) float4 sp[NP];       // x, y, r, 0
    const int tid = threadIdx.x;
    const int n = blockIdx.x >> 1;
    const float* pb = pts + (size_t)n * NP * 2;
    for (int i = tid; i < NP; i += 256) {
        float x = pb[i * 2], y = pb[i * 2 + 1];
        float r = x * x + y * y;                  // matches np: mul, mul, add
        sp[i] = make_float4(x, y, r, 0.f);
    }
    __syncthreads();
    const int p = ((blockIdx.x & 1) << 8) + tid;
    const float xp = sp[p].x, yp = sp[p].y, rp = sp[p].z;

    unsigned long long key[17];
#pragma unroll
    for (int j = 0; j < 17; ++j) key[j] = ~0ull;

    for (int q = 0; q < NP; ++q) {
        float4 sq = sp[q];
        float m = xp * sq.x + yp * sq.y;          // einsum inner order
        float d = (rp - 2.0f * m) + sq.z;         // (r - 2m) + r^T order
        unsigned int ub = __float_as_uint(d);
        ub = (ub & 0x80000000u) ? ~ub : (ub | 0x80000000u);
        unsigned long long kk = ((unsigned long long)ub << 32) | (unsigned)q;
        if (kk < key[16]) {                       // qualifies for top-17
#pragma unroll
            for (int j = 16; j >= 1; --j) {
                unsigned long long prev = key[j - 1], cur = key[j];
                unsigned long long nc = kk < cur ? kk : cur;
                key[j] = (kk < prev) ? prev : nc;
            }
            if (kk < key[0]) key[0] = kk;
        }
    }
    int* ob = idx + ((size_t)n * NP + p) * KNN;
#pragma unroll
    for (int k = 0; k < KNN; ++k)                 // drop slot 0 (self)
        ob[k] = (int)(unsigned)(key[k + 1] & 0xffffffffu);
}

// ---------------- BN finalize: partials -> scale/shift ----------------
__global__ void finalize_bn(const float* __restrict__ part, float* __restrict__ bn,
                            const float* g0, const float* b0, const float* g1,
                            const float* b1, const float* g2, const float* b2,
                            const float* scg, const float* scb) {
    int L = blockIdx.x;                           // 0,1,2 = layers; 3 = shortcut
    int o = threadIdx.x;                          // 64 threads
    const float* g = (L == 0) ? g0 : (L == 1) ? g1 : (L == 2) ? g2 : scg;
    const float* b = (L == 0) ? b0 : (L == 1) ? b1 : (L == 2) ? b2 : scb;
    float cnt = (L == 3) ? (float)(NB * NP) : (float)(NB * NP * KNN);
    float s = 0.f, ss = 0.f;
    for (int slot = 0; slot < 64; ++slot) {
        s  += part[((L * 64 + slot) * 2 + 0) * 64 + o];
        ss += part[((L * 64 + slot) * 2 + 1) * 64 + o];
    }
    float mu  = s / cnt;
    float var = fmaxf(ss / cnt - mu * mu, 0.f);
    float sc  = g[o] * rsqrtf(var + 1e-5f);
    bn[L * 128 + o]      = sc;
    bn[L * 128 + 64 + o] = b[o] - mu * sc;
}

// ---------------- helpers ----------------
__device__ __forceinline__ void loadrow(float* w, const float* __restrict__ src) {
#pragma unroll
    for (int c4 = 0; c4 < 16; ++c4) {
        float4 v = ((const float4*)src)[c4];
        w[c4 * 4 + 0] = v.x; w[c4 * 4 + 1] = v.y;
        w[c4 * 4 + 2] = v.z; w[c4 * 4 + 3] = v.w;
    }
}

// ---------------- MLP recompute phases ----------------
// PHASE 1: y1 -> stats L0 + shortcut stats L3
// PHASE 2: y1 -> a1 -> y2 -> stats L1
// PHASE 3: ... -> y3 -> stats L2
// PHASE 4: ... -> a3 -> mean_k + shortcut -> out
template <int PHASE>
__global__ __launch_bounds__(256, 2)
void mlp_phase(const float* __restrict__ feats, const int* __restrict__ idx,
               const float* __restrict__ Wc, const float* __restrict__ Wn,
               const float* __restrict__ W1, const float* __restrict__ W2,
               const float* __restrict__ scW, const float* __restrict__ bn,
               float* __restrict__ part, float* __restrict__ out) {
    __shared__ __align__(16) float act[BPP][17][CH];  // row 0: center; 1..16: nbrs/activations
    __shared__ float tc[BPP][CH];
    __shared__ float red[4][CH];
    __shared__ float red2[4][CH];
    __shared__ float m4[4][BPP][CH];

    const int tid = threadIdx.x;
    const int o = tid & 63;
    const int kq = tid >> 6;                      // 0..3 (one wave each)
    const int nb = blockIdx.x;
    const int n = nb >> 7;                        // NP/BPP = 128 tiles per n
    const int p0 = (nb & 127) * BPP;
    const float* fb = feats + (size_t)n * NP * CH;
    const int* ib = idx + ((size_t)n * NP + p0) * KNN;

    // ---- stage center + 16 neighbor feature rows per point ----
    for (int r = kq; r < BPP * 17; r += 4) {
        int p = r / 17, slot = r - p * 17;
        int src = (slot == 0) ? (p0 + p) : ib[p * KNN + slot - 1];
        act[p][slot][o] = fb[src * CH + o];
    }
    __syncthreads();

    float wreg[CH];
    float y[BPP * 4];

    // ---- center term tc[p][o] = Wc[o] . center[p]  (thread handles p = kq) ----
    loadrow(wreg, Wc + o * CH);
    {
        float acc = 0.f;
#pragma unroll
        for (int c = 0; c < CH; c += 4) {
            float4 a = *(const float4*)&act[kq][0][c];
            acc = fmaf(wreg[c + 0], a.x, acc);
            acc = fmaf(wreg[c + 1], a.y, acc);
            acc = fmaf(wreg[c + 2], a.z, acc);
            acc = fmaf(wreg[c + 3], a.w, acc);
        }
        tc[kq][o] = acc;
    }
    __syncthreads();

    auto do_layer = [&](bool useTc) {
#pragma unroll
        for (int p = 0; p < BPP; ++p) {
#pragma unroll
            for (int j = 0; j < 4; ++j) {
                float acc = useTc ? tc[p][o] : 0.f;
                const float* ar = act[p][1 + kq * 4 + j];
#pragma unroll
                for (int c = 0; c < CH; c += 4) {
                    float4 a = *(const float4*)&ar[c];
                    acc = fmaf(wreg[c + 0], a.x, acc);
                    acc = fmaf(wreg[c + 1], a.y, acc);
                    acc = fmaf(wreg[c + 2], a.z, acc);
                    acc = fmaf(wreg[c + 3], a.w, acc);
                }
                y[p * 4 + j] = acc;
            }
        }
    };

    auto accum_stats = [&](int L) {
        float s = 0.f, ss = 0.f;
#pragma unroll
        for (int i = 0; i < BPP * 4; ++i) { s += y[i]; ss += y[i] * y[i]; }
        red[kq][o] = s; red2[kq][o] = ss;
        __syncthreads();
        if (kq == 0) {
            int slot = nb & 63;
            float S  = red[0][o] + red[1][o] + red[2][o] + red[3][o];
            float SS = red2[0][o] + red2[1][o] + red2[2][o] + red2[3][o];
            atomicAdd(&part[((L * 64 + slot) * 2 + 0) * 64 + o], S);
            atomicAdd(&part[((L * 64 + slot) * 2 + 1) * 64 + o], SS);
        }
        __syncthreads();
    };

    auto bn_relu_store = [&](int L) {
        float sc = bn[L * 128 + o];
        float sh = bn[L * 128 + 64 + o];
        __syncthreads();                           // all reads of prev activations done
#pragma unroll
        for (int p = 0; p < BPP; ++p)
#pragma unroll
            for (int j = 0; j < 4; ++j)
                act[p][1 + kq * 4 + j][o] = fmaxf(fmaf(y[p * 4 + j], sc, sh), 0.f);
        __syncthreads();
    };

    // ---- layer 1: y1 = tc + Wn . nf ----
    loadrow(wreg, Wn + o * CH);
    do_layer(true);

    if (PHASE == 1) {
        accum_stats(0);
        // shortcut pre-BN stats (one sample per thread, p = kq)
        loadrow(wreg, scW + o * CH);
        float accs = 0.f;
#pragma unroll
        for (int c = 0; c < CH; c += 4) {
            float4 a = *(const float4*)&act[kq][0][c];
            accs = fmaf(wreg[c + 0], a.x, accs);
            accs = fmaf(wreg[c + 1], a.y, accs);
            accs = fmaf(wreg[c + 2], a.z, accs);
            accs = fmaf(wreg[c + 3], a.w, accs);
        }
        red[kq][o] = accs; red2[kq][o] = accs * accs;
        __syncthreads();
        if (kq == 0) {
            int slot = nb & 63;
            float S  = red[0][o] + red[1][o] + red[2][o] + red[3][o];
            float SS = red2[0][o] + red2[1][o] + red2[2][o] + red2[3][o];
            atomicAdd(&part[((3 * 64 + slot) * 2 + 0) * 64 + o], S);
            atomicAdd(&part[((3 * 64 + slot) * 2 + 1) * 64 + o], SS);
        }
        return;
    }

    bn_relu_store(0);
    loadrow(wreg, W1 + o * CH);
    do_layer(false);
    if (PHASE == 2) { accum_stats(1); return; }

    bn_relu_store(1);
    loadrow(wreg, W2 + o * CH);
    do_layer(false);
    if (PHASE == 3) { accum_stats(2); return; }

    // ---- PHASE 4: a3 = relu(bn2(y3)); mean over k; + shortcut ----
    {
        float s2 = bn[2 * 128 + o], h2 = bn[2 * 128 + 64 + o];
#pragma unroll
        for (int p = 0; p < BPP; ++p) {
            float mp = 0.f;
#pragma unroll
            for (int j = 0; j < 4; ++j)
                mp += fmaxf(fmaf(y[p * 4 + j], s2, h2), 0.f);
            m4[kq][p][o] = mp;
        }
        __syncthreads();
        // shortcut for p = kq
        loadrow(wreg, scW + o * CH);
        float accs = 0.f;
#pragma unroll
        for (int c = 0; c < CH; c += 4) {
            float4 a = *(const float4*)&act[kq][0][c];
            accs = fmaf(wreg[c + 0], a.x, accs);
            accs = fmaf(wreg[c + 1], a.y, accs);
            accs = fmaf(wreg[c + 2], a.z, accs);
            accs = fmaf(wreg[c + 3], a.w, accs);
        }
        float s3 = bn[3 * 128 + o], h3 = bn[3 * 128 + 64 + o];
        float scv = fmaxf(fmaf(accs, s3, h3), 0.f);
        float xm = (m4[0][kq][o] + m4[1][kq][o] + m4[2][kq][o] + m4[3][kq][o]) * (1.f / 16.f);
        out[((size_t)(n * NP + p0 + kq)) * CH + o] = xm + scv;
    }
}

extern "C" void kernel_launch(void* const* d_in, const int* in_sizes, int n_in,
                              void* d_out, int out_size, void* d_ws, size_t ws_size,
                              hipStream_t stream) {
    const float* points = (const float*)d_in[0];
    const float* feats  = (const float*)d_in[1];
    const float* W0  = (const float*)d_in[2];
    const float* g0  = (const float*)d_in[3];
    const float* b0  = (const float*)d_in[4];
    const float* W1  = (const float*)d_in[5];
    const float* g1  = (const float*)d_in[6];
    const float* b1  = (const float*)d_in[7];
    const float* W2  = (const float*)d_in[8];
    const float* g2  = (const float*)d_in[9];
    const float* b2  = (const float*)d_in[10];
    const float* scW = (const float*)d_in[11];
    const float* scg = (const float*)d_in[12];
    const float* scb = (const float*)d_in[13];
    float* out = (float*)d_out;

    char* ws = (char*)d_ws;
    int*   idx  = (int*)(ws + OFF_IDX);
    float* part = (float*)(ws + OFF_PART);
    float* bn   = (float*)(ws + OFF_BN);
    float* Wc   = (float*)(ws + OFF_WC);
    float* Wn   = (float*)(ws + OFF_WN);

    hipMemsetAsync(part, 0, PART_BYTES, stream);
    prep_weights<<<16, 256, 0, stream>>>(W0, Wc, Wn);
    knn_kernel<<<NB * 2, 256, 0, stream>>>(points, idx);

    dim3 pg(NB * (NP / BPP));                     // 16384 blocks
    mlp_phase<1><<<pg, 256, 0, stream>>>(feats, idx, Wc, Wn, W1, W2, scW, bn, part, out);
    finalize_bn<<<4, 64, 0, stream>>>(part, bn, g0, b0, g1, b1, g2, b2, scg, scb);
    mlp_phase<2><<<pg, 256, 0, stream>>>(feats, idx, Wc, Wn, W1, W2, scW, bn, part, out);
    finalize_bn<<<4, 64, 0, stream>>>(part, bn, g0, b0, g1, b1, g2, b2, scg, scb);
    mlp_phase<3><<<pg, 256, 0, stream>>>(feats, idx, Wc, Wn, W1, W2, scW, bn, part, out);
    finalize_bn<<<4, 64, 0, stream>>>(part, bn, g0, b0, g1, b1, g2, b2, scg, scb);
    mlp_phase<4><<<pg, 256, 0, stream>>>(feats, idx, Wc, Wn, W1, W2, scW, bn, part, out);
}

// Round 2
// 789.093 us; speedup vs baseline: 3.4347x; 3.4347x over previous
//
#include <hip/hip_runtime.h>
#include <stdint.h>

typedef unsigned short u16;
typedef __attribute__((ext_vector_type(8))) short bf8v;    // 8 bf16 MFMA frag
typedef __attribute__((ext_vector_type(4))) float f32x4;   // C/D frag

#define NB   128
#define NP   512
#define KNN  16
#define CH   64
#define NPB  8                       // points per block
#define GPH  (NB * NP / NPB)         // 8192 blocks per phase
#define SLOTS 512

// ---------------- workspace layout (bytes) ----------------
#define OFF_IDX   0                  // 4 MB: knn indices
#define OFF_PART  0x400000           // 1 MB: [L][slot][sum/ssq][ch]
#define PART_BYTES (4 * SLOTS * 2 * 64 * 4)
#define OFF_BN    0x500000           // 2 KB: [L][scale/shift][ch]
#define OFF_WN    0x500800           // 8 KB bf16 [o][c]
#define OFF_WC    0x502800
#define OFF_W1B   0x504800
#define OFF_W2B   0x506800
#define OFF_SCWT  0x508800           // 16 KB f32 [c][o]

__device__ __forceinline__ u16 f2bf(float f) {
    union { float f; unsigned u; } v; v.f = f;
    unsigned r = v.u + 0x7fffu + ((v.u >> 16) & 1u);       // RNE
    return (u16)(r >> 16);
}
__device__ __forceinline__ float bf2f(u16 b) {
    union { unsigned u; float f; } v; v.u = ((unsigned)b) << 16;
    return v.f;
}
struct alignas(16) US8 { u16 v[8]; };
__device__ __forceinline__ US8 pack8(float4 f0, float4 f1) {
    US8 u;
    u.v[0]=f2bf(f0.x); u.v[1]=f2bf(f0.y); u.v[2]=f2bf(f0.z); u.v[3]=f2bf(f0.w);
    u.v[4]=f2bf(f1.x); u.v[5]=f2bf(f1.y); u.v[6]=f2bf(f1.z); u.v[7]=f2bf(f1.w);
    return u;
}

// ---------------- weight prep ----------------
__global__ void prep_weights(const float* __restrict__ W0, const float* __restrict__ W1,
                             const float* __restrict__ W2, const float* __restrict__ scW,
                             u16* Wn, u16* Wc, u16* W1b, u16* W2b, float* scWT) {
    int i = blockIdx.x * 256 + threadIdx.x;                // i = o*64 + c
    if (i < 4096) {
        int o = i >> 6, c = i & 63;
        float a = W0[o * 128 + c], b = W0[o * 128 + 64 + c];
        Wc[i] = f2bf(a - b);
        Wn[i] = f2bf(b);
        W1b[i] = f2bf(W1[i]);
        W2b[i] = f2bf(W2[i]);
        scWT[c * 64 + o] = scW[i];
    }
}

// ---------------- KNN (unchanged from R1 — verified exact) ----------------
__global__ __launch_bounds__(256)
void knn_kernel(const float* __restrict__ pts, int* __restrict__ idx) {
#pragma clang fp contract(off)
    __shared__ __align__(16) float4 sp[NP];
    const int tid = threadIdx.x;
    const int n = blockIdx.x >> 1;
    const float* pb = pts + (size_t)n * NP * 2;
    for (int i = tid; i < NP; i += 256) {
        float x = pb[i * 2], y = pb[i * 2 + 1];
        float r = x * x + y * y;
        sp[i] = make_float4(x, y, r, 0.f);
    }
    __syncthreads();
    const int p = ((blockIdx.x & 1) << 8) + tid;
    const float xp = sp[p].x, yp = sp[p].y, rp = sp[p].z;

    unsigned long long key[17];
#pragma unroll
    for (int j = 0; j < 17; ++j) key[j] = ~0ull;

    for (int q = 0; q < NP; ++q) {
        float4 sq = sp[q];
        float m = xp * sq.x + yp * sq.y;
        float d = (rp - 2.0f * m) + sq.z;
        unsigned int ub = __float_as_uint(d);
        ub = (ub & 0x80000000u) ? ~ub : (ub | 0x80000000u);
        unsigned long long kk = ((unsigned long long)ub << 32) | (unsigned)q;
        if (kk < key[16]) {
#pragma unroll
            for (int j = 16; j >= 1; --j) {
                unsigned long long prev = key[j - 1], cur = key[j];
                unsigned long long nc = kk < cur ? kk : cur;
                key[j] = (kk < prev) ? prev : nc;
            }
            if (kk < key[0]) key[0] = kk;
        }
    }
    int* ob = idx + ((size_t)n * NP + p) * KNN;
#pragma unroll
    for (int k = 0; k < KNN; ++k)
        ob[k] = (int)(unsigned)(key[k + 1] & 0xffffffffu);
}

// ---------------- BN finalize ----------------
__global__ void finalize_bn(const float* __restrict__ part, float* __restrict__ bn,
                            const float* g0, const float* b0, const float* g1,
                            const float* b1, const float* g2, const float* b2,
                            const float* scg, const float* scb, int mapA, int mapB) {
    int L = (blockIdx.x == 0) ? mapA : mapB;
    int o = threadIdx.x;                                   // 64 threads
    const float* g = (L == 0) ? g0 : (L == 1) ? g1 : (L == 2) ? g2 : scg;
    const float* b = (L == 0) ? b0 : (L == 1) ? b1 : (L == 2) ? b2 : scb;
    float cnt = (L == 3) ? (float)(NB * NP) : (float)(NB * NP * KNN);
    float s = 0.f, ss = 0.f;
    for (int slot = 0; slot < SLOTS; ++slot) {
        s  += part[((L * SLOTS + slot) * 2 + 0) * 64 + o];
        ss += part[((L * SLOTS + slot) * 2 + 1) * 64 + o];
    }
    float mu  = s / cnt;
    float var = fmaxf(ss / cnt - mu * mu, 0.f);
    float sc  = g[o] * rsqrtf(var + 1e-5f);
    bn[L * 128 + o]      = sc;
    bn[L * 128 + 64 + o] = b[o] - mu * sc;
}

#define MFMA16(a, b, c) __builtin_amdgcn_mfma_f32_16x16x32_bf16(a, b, c, 0, 0, 0)

// ---------------- MFMA MLP phases (recompute pipeline) ----------------
template <int PHASE>
__global__ __launch_bounds__(256, 4)
void mlp_phase(const float* __restrict__ feats, const int* __restrict__ idx,
               const u16* __restrict__ Wn, const u16* __restrict__ Wc,
               const u16* __restrict__ W1b, const u16* __restrict__ W2b,
               const float* __restrict__ scWT, const float* __restrict__ bn,
               float* __restrict__ part, float* __restrict__ out) {
    __shared__ char Ab[128 * 128];        // 128 rows x 64ch bf16, XOR-swizzled
    __shared__ char cenB[NPB * 128];      // 8 center rows bf16, linear
    __shared__ float scv[NPB][64];
    __shared__ float sred[4][64];
    __shared__ float ssred[4][64];

    const int tid = threadIdx.x;
    const int lane = tid & 63;
    const int w = tid >> 6;               // wave 0..3, owns rows w*32..w*32+31
    const int l15 = lane & 15;
    const int g4 = lane >> 4;             // 0..3
    const int nb = blockIdx.x;
    const int n = nb >> 6;
    const int p0 = (nb & 63) * NPB;
    const float* fb = feats + (size_t)n * NP * CH;

    // ---- gather neighbors -> bf16 LDS (wave-local rows) ----
    {
        int r = tid >> 1, h = tid & 1;
        int pl = r >> 4, k = r & 15;
        int src = idx[((size_t)(n * NP + p0 + pl)) * KNN + k];
        const float4* gp = (const float4*)(fb + src * CH + h * 32);
        int rb = r * 128, sw = (r & 7) << 4;
#pragma unroll
        for (int q = 0; q < 4; ++q) {
            US8 u = pack8(gp[2 * q], gp[2 * q + 1]);
            *(US8*)(Ab + rb + ((h * 64 + q * 16) ^ sw)) = u;
        }
    }
    if (tid < 64) {                       // center rows
        int p = tid >> 3, jj = tid & 7;
        const float4* gp = (const float4*)(fb + (size_t)(p0 + p) * CH + jj * 8);
        *(US8*)(cenB + p * 128 + jj * 16) = pack8(gp[0], gp[1]);
    }
    __syncthreads();

    f32x4 acc[2][4];
#pragma unroll
    for (int rt = 0; rt < 2; ++rt)
#pragma unroll
        for (int ct = 0; ct < 4; ++ct) acc[rt][ct] = (f32x4){0.f, 0.f, 0.f, 0.f};

    const int r0 = w * 32 + l15, r1 = r0 + 16;
    const int sw0 = (r0 & 7) << 4;        // == (r1&7)<<4

    auto layerA = [&](const u16* Wb) {    // A from swizzled Ab
#pragma unroll
        for (int ks = 0; ks < 2; ++ks) {
            bf8v a0 = *(const bf8v*)(Ab + r0 * 128 + ((ks * 64 + g4 * 16) ^ sw0));
            bf8v a1 = *(const bf8v*)(Ab + r1 * 128 + ((ks * 64 + g4 * 16) ^ sw0));
#pragma unroll
            for (int ct = 0; ct < 4; ++ct) {
                bf8v b = *(const bf8v*)((const char*)Wb + (ct * 16 + l15) * 128 + ks * 64 + g4 * 16);
                acc[0][ct] = MFMA16(a0, b, acc[0][ct]);
                acc[1][ct] = MFMA16(a1, b, acc[1][ct]);
            }
        }
    };
    auto layerC = [&](const u16* Wb) {    // A from center buffer (broadcast)
#pragma unroll
        for (int ks = 0; ks < 2; ++ks) {
            bf8v a0 = *(const bf8v*)(cenB + (2 * w) * 128 + ks * 64 + g4 * 16);
            bf8v a1 = *(const bf8v*)(cenB + (2 * w + 1) * 128 + ks * 64 + g4 * 16);
#pragma unroll
            for (int ct = 0; ct < 4; ++ct) {
                bf8v b = *(const bf8v*)((const char*)Wb + (ct * 16 + l15) * 128 + ks * 64 + g4 * 16);
                acc[0][ct] = MFMA16(a0, b, acc[0][ct]);
                acc[1][ct] = MFMA16(a1, b, acc[1][ct]);
            }
        }
    };

    auto stats = [&](int L) {
        float s[4], q[4];
#pragma unroll
        for (int ct = 0; ct < 4; ++ct) {
            float a = 0.f, b = 0.f;
#pragma unroll
            for (int rt = 0; rt < 2; ++rt)
#pragma unroll
                for (int j = 0; j < 4; ++j) { float v = acc[rt][ct][j]; a += v; b += v * v; }
            a += __shfl_xor(a, 16); a += __shfl_xor(a, 32);
            b += __shfl_xor(b, 16); b += __shfl_xor(b, 32);
            s[ct] = a; q[ct] = b;
        }
        if (lane < 16) {
#pragma unroll
            for (int ct = 0; ct < 4; ++ct) {
                sred[w][ct * 16 + lane] = s[ct];
                ssred[w][ct * 16 + lane] = q[ct];
            }
        }
        __syncthreads();
        if (tid < 128) {
            int j = tid >> 6, ch = tid & 63;
            float t;
            if (j == 0) t = sred[0][ch] + sred[1][ch] + sred[2][ch] + sred[3][ch];
            else        t = ssred[0][ch] + ssred[1][ch] + ssred[2][ch] + ssred[3][ch];
            atomicAdd(&part[((L * SLOTS + (nb & (SLOTS - 1))) * 2 + j) * 64 + ch], t);
        }
    };

    auto bnwb = [&](int L) {              // BN+ReLU, write back to Ab, zero acc
#pragma unroll
        for (int ct = 0; ct < 4; ++ct) {
            int ch = ct * 16 + l15;
            float sc = bn[L * 128 + ch], sh = bn[L * 128 + 64 + ch];
#pragma unroll
            for (int rt = 0; rt < 2; ++rt)
#pragma unroll
                for (int j = 0; j < 4; ++j) {
                    int gr = w * 32 + rt * 16 + g4 * 4 + j;
                    float v = fmaxf(fmaf(acc[rt][ct][j], sc, sh), 0.f);
                    *(u16*)(Ab + gr * 128 + ((ch * 2) ^ ((gr & 7) << 4))) = f2bf(v);
                    acc[rt][ct][j] = 0.f;
                }
        }
    };

    // ---- layer 1: Wn over neighbors + Wc over centers ----
    layerA(Wn);
    layerC(Wc);

    if (PHASE == 1) {
        stats(0);
        // shortcut pre-BN values + stats
        {
            int p = tid >> 5, o = tid & 31;
            float a0 = 0.f, a1 = 0.f;
            const char* cp = cenB + p * 128;
#pragma unroll 16
            for (int c = 0; c < 64; ++c) {
                float cv = bf2f(*(const u16*)(cp + c * 2));
                a0 = fmaf(cv, scWT[c * 64 + o], a0);
                a1 = fmaf(cv, scWT[c * 64 + o + 32], a1);
            }
            scv[p][o] = a0; scv[p][o + 32] = a1;
        }
        __syncthreads();
        if (tid < 128) {
            int j = tid >> 6, ch = tid & 63;
            float t = 0.f;
            if (j == 0) { for (int p = 0; p < NPB; ++p) t += scv[p][ch]; }
            else        { for (int p = 0; p < NPB; ++p) t += scv[p][ch] * scv[p][ch]; }
            atomicAdd(&part[((3 * SLOTS + (nb & (SLOTS - 1))) * 2 + j) * 64 + ch], t);
        }
        return;
    }

    bnwb(0);
    layerA(W1b);
    if (PHASE == 2) { stats(1); return; }

    bnwb(1);
    layerA(W2b);
    if (PHASE == 3) { stats(2); return; }

    // ---- PHASE 4: shortcut + bn2-relu + mean_k + output ----
    {
        int p = tid >> 5, o = tid & 31;
        float a0 = 0.f, a1 = 0.f;
        const char* cp = cenB + p * 128;
#pragma unroll 16
        for (int c = 0; c < 64; ++c) {
            float cv = bf2f(*(const u16*)(cp + c * 2));
            a0 = fmaf(cv, scWT[c * 64 + o], a0);
            a1 = fmaf(cv, scWT[c * 64 + o + 32], a1);
        }
        float s3a = bn[3 * 128 + o],      h3a = bn[3 * 128 + 64 + o];
        float s3b = bn[3 * 128 + 32 + o], h3b = bn[3 * 128 + 96 + o];
        scv[p][o]      = fmaxf(fmaf(a0, s3a, h3a), 0.f);
        scv[p][o + 32] = fmaxf(fmaf(a1, s3b, h3b), 0.f);
    }
    {
        float m0[4], m1[4];
#pragma unroll
        for (int ct = 0; ct < 4; ++ct) {
            int ch = ct * 16 + l15;
            float sc = bn[2 * 128 + ch], sh = bn[2 * 128 + 64 + ch];
            float ma = 0.f, mb = 0.f;
#pragma unroll
            for (int j = 0; j < 4; ++j) {
                ma += fmaxf(fmaf(acc[0][ct][j], sc, sh), 0.f);
                mb += fmaxf(fmaf(acc[1][ct][j], sc, sh), 0.f);
            }
            ma += __shfl_xor(ma, 16); ma += __shfl_xor(ma, 32);
            mb += __shfl_xor(mb, 16); mb += __shfl_xor(mb, 32);
            m0[ct] = ma; m1[ct] = mb;
        }
        int ph = g4 >> 1;                 // 0: p=2w, 1: p=2w+1
        int p = 2 * w + ph;
        int cb = (g4 & 1) * 2;
        float* ob = out + ((size_t)(n * NP + p0 + p)) * CH;
#pragma unroll
        for (int ii = 0; ii < 2; ++ii) {
            int cc = cb + ii;
            int ch = cc * 16 + l15;
            float mlo = m0[cc], mhi = m1[cc];
            float mv = ph ? mhi : mlo;
            ob[ch] = mv * 0.0625f + scv[p][ch];
        }
    }
}

extern "C" void kernel_launch(void* const* d_in, const int* in_sizes, int n_in,
                              void* d_out, int out_size, void* d_ws, size_t ws_size,
                              hipStream_t stream) {
    const float* points = (const float*)d_in[0];
    const float* feats  = (const float*)d_in[1];
    const float* W0  = (const float*)d_in[2];
    const float* g0  = (const float*)d_in[3];
    const float* b0  = (const float*)d_in[4];
    const float* W1  = (const float*)d_in[5];
    const float* g1  = (const float*)d_in[6];
    const float* b1  = (const float*)d_in[7];
    const float* W2  = (const float*)d_in[8];
    const float* g2  = (const float*)d_in[9];
    const float* b2  = (const float*)d_in[10];
    const float* scW = (const float*)d_in[11];
    const float* scg = (const float*)d_in[12];
    const float* scb = (const float*)d_in[13];
    float* out = (float*)d_out;

    char* ws = (char*)d_ws;
    int*   idx  = (int*)(ws + OFF_IDX);
    float* part = (float*)(ws + OFF_PART);
    float* bn   = (float*)(ws + OFF_BN);
    u16*   Wn   = (u16*)(ws + OFF_WN);
    u16*   Wc   = (u16*)(ws + OFF_WC);
    u16*   W1b  = (u16*)(ws + OFF_W1B);
    u16*   W2b  = (u16*)(ws + OFF_W2B);
    float* scWT = (float*)(ws + OFF_SCWT);

    hipMemsetAsync(part, 0, PART_BYTES, stream);
    prep_weights<<<16, 256, 0, stream>>>(W0, W1, W2, scW, Wn, Wc, W1b, W2b, scWT);
    knn_kernel<<<NB * 2, 256, 0, stream>>>(points, idx);

    mlp_phase<1><<<GPH, 256, 0, stream>>>(feats, idx, Wn, Wc, W1b, W2b, scWT, bn, part, out);
    finalize_bn<<<2, 64, 0, stream>>>(part, bn, g0, b0, g1, b1, g2, b2, scg, scb, 0, 3);
    mlp_phase<2><<<GPH, 256, 0, stream>>>(feats, idx, Wn, Wc, W1b, W2b, scWT, bn, part, out);
    finalize_bn<<<1, 64, 0, stream>>>(part, bn, g0, b0, g1, b1, g2, b2, scg, scb, 1, 1);
    mlp_phase<3><<<GPH, 256, 0, stream>>>(feats, idx, Wn, Wc, W1b, W2b, scWT, bn, part, out);
    finalize_bn<<<1, 64, 0, stream>>>(part, bn, g0, b0, g1, b1, g2, b2, scg, scb, 2, 2);
    mlp_phase<4><<<GPH, 256, 0, stream>>>(feats, idx, Wn, Wc, W1b, W2b, scWT, bn, part, out);
}